// Round 13
// baseline (11364.729 us; speedup 1.0000x reference)
//
#include <hip/hip_runtime.h>
#include <cstdint>
#include <cstddef>

// All float tensors are f32 on device (harness: float32 -> const float*).
// edge_index is integer -> const int* per harness; a cheap runtime detector
// handles a hypothetical int64 staging too (stride 2 vs 1, low word read).

// ---------- edge dtype detection ----------
__global__ void detect_estride(const unsigned int* __restrict__ w, int* __restrict__ sp) {
    __shared__ int nz;
    if (threadIdx.x == 0) nz = 0;
    __syncthreads();
    int my = 0;
    for (int i = threadIdx.x; i < 4096; i += 256)
        if (w[2 * i + 1] != 0u) my++;
    if (my) atomicAdd(&nz, my);
    __syncthreads();
    if (threadIdx.x == 0) *sp = (nz == 0) ? 2 : 1;
}

// ---------- graph structure ----------
__global__ void count_edges(const unsigned int* __restrict__ w, const int* __restrict__ sp,
                            float* __restrict__ cnt, int E) {
    int e = blockIdx.x * blockDim.x + threadIdx.x;
    if (e >= E) return;
    int st = *sp;
    int dd = (int)w[(size_t)(E + e) * st];
    atomicAdd(&cnt[dd], 1.0f);
}

__global__ void node_stats(const float* __restrict__ cnt, float* __restrict__ dinv,
                           float* __restrict__ rdeg, float* __restrict__ rm, int n) {
    int i = blockIdx.x * blockDim.x + threadIdx.x;
    if (i >= n) return;
    float c = cnt[i];
    float d = c + 1.0f;
    dinv[i] = rsqrtf(d);
    rdeg[i] = 1.0f / d;
    rm[i]   = 1.0f / fmaxf(c, 1.0f);
}

// ---------- edge scatter (segment_sum of features) ----------
// one float4 chunk per thread; d = 4 << d4shift features per node
__global__ void scatter_f32(const float* __restrict__ feat, const unsigned int* __restrict__ w,
                            const int* __restrict__ sp, float* __restrict__ out,
                            int E, int d4shift) {
    long long t = (long long)blockIdx.x * blockDim.x + threadIdx.x;
    long long total = (long long)E << d4shift;
    if (t >= total) return;
    int e = (int)(t >> d4shift);
    int c = (int)(t & ((1 << d4shift) - 1));
    int st = *sp;
    int s  = (int)w[(size_t)e * st];
    int dd = (int)w[(size_t)(E + e) * st];
    int dshift = d4shift + 2;
    const float4 v = *(const float4*)(feat + ((size_t)s << dshift) + (c << 2));
    float* o = out + ((size_t)dd << dshift) + (c << 2);
    atomicAdd(o + 0, v.x);
    atomicAdd(o + 1, v.y);
    atomicAdd(o + 2, v.z);
    atomicAdd(o + 3, v.w);
}

// ---------- fused GEMM: C = act( scale(A1)@B1 [+ A2@B2] [+ bias] ) ----------
// BM=64, BN=64, BK=32, 256 threads, 4x4 micro-tile per thread.
template<bool TWO, bool RELU>
__global__ __launch_bounds__(256)
void gemm_tile(const float* __restrict__ A1, const float* __restrict__ A2,
               const float* __restrict__ B1, const float* __restrict__ B2,
               const float* __restrict__ bias, const float* __restrict__ rscale,
               float* __restrict__ C, int M, int Nc, int K) {
    __shared__ float As1[32][64];
    __shared__ float Bs1[32][64];
    __shared__ float As2[TWO ? 32 : 1][64];
    __shared__ float Bs2[TWO ? 32 : 1][64];

    const int tid  = threadIdx.x;
    const int row0 = blockIdx.y * 64;
    const int col0 = blockIdx.x * 64;
    const int crow = (tid >> 4) << 2;
    const int ccol = (tid & 15) << 2;

    float acc[4][4] = {};

    for (int k0 = 0; k0 < K; k0 += 32) {
        // A tiles: 64 rows x 32 k, stored transposed As[k][row]
#pragma unroll
        for (int i = 0; i < 2; ++i) {
            int idx = tid + i * 256;
            int r  = idx >> 3;
            int kc = (idx & 7) << 2;
            int grow = row0 + r;
            if (grow > M - 1) grow = M - 1;
            float sc = rscale ? rscale[grow] : 1.0f;
            float4 a = *(const float4*)(A1 + (size_t)grow * K + k0 + kc);
            As1[kc + 0][r] = a.x * sc;
            As1[kc + 1][r] = a.y * sc;
            As1[kc + 2][r] = a.z * sc;
            As1[kc + 3][r] = a.w * sc;
            if constexpr (TWO) {
                float4 a2 = *(const float4*)(A2 + (size_t)grow * K + k0 + kc);
                As2[kc + 0][r] = a2.x;
                As2[kc + 1][r] = a2.y;
                As2[kc + 2][r] = a2.z;
                As2[kc + 3][r] = a2.w;
            }
        }
        // B tiles: 32 k x 64 cols
#pragma unroll
        for (int i = 0; i < 2; ++i) {
            int idx = tid + i * 256;
            int kk = idx >> 4;
            int c4 = (idx & 15) << 2;
            *(float4*)&Bs1[kk][c4] = *(const float4*)(B1 + (size_t)(k0 + kk) * Nc + col0 + c4);
            if constexpr (TWO)
                *(float4*)&Bs2[kk][c4] = *(const float4*)(B2 + (size_t)(k0 + kk) * Nc + col0 + c4);
        }
        __syncthreads();

#pragma unroll
        for (int k = 0; k < 32; ++k) {
            float4 a1 = *(const float4*)&As1[k][crow];
            float4 b1 = *(const float4*)&Bs1[k][ccol];
            float av[4] = {a1.x, a1.y, a1.z, a1.w};
            float bv[4] = {b1.x, b1.y, b1.z, b1.w};
#pragma unroll
            for (int r = 0; r < 4; ++r)
#pragma unroll
                for (int c = 0; c < 4; ++c)
                    acc[r][c] += av[r] * bv[c];
            if constexpr (TWO) {
                float4 a2 = *(const float4*)&As2[k][crow];
                float4 b2 = *(const float4*)&Bs2[k][ccol];
                float av2[4] = {a2.x, a2.y, a2.z, a2.w};
                float bv2[4] = {b2.x, b2.y, b2.z, b2.w};
#pragma unroll
                for (int r = 0; r < 4; ++r)
#pragma unroll
                    for (int c = 0; c < 4; ++c)
                        acc[r][c] += av2[r] * bv2[c];
            }
        }
        __syncthreads();
    }

    float bv[4] = {0.f, 0.f, 0.f, 0.f};
    if (bias) {
        float4 b = *(const float4*)(bias + col0 + ccol);
        bv[0] = b.x; bv[1] = b.y; bv[2] = b.z; bv[3] = b.w;
    }
#pragma unroll
    for (int r = 0; r < 4; ++r) {
        int row = row0 + crow + r;
        if (row < M) {
            float4 o;
            o.x = acc[r][0] + bv[0];
            o.y = acc[r][1] + bv[1];
            o.z = acc[r][2] + bv[2];
            o.w = acc[r][3] + bv[3];
            if constexpr (RELU) {
                o.x = fmaxf(o.x, 0.f); o.y = fmaxf(o.y, 0.f);
                o.z = fmaxf(o.z, 0.f); o.w = fmaxf(o.w, 0.f);
            }
            *(float4*)(C + (size_t)row * Nc + col0 + ccol) = o;
        }
    }
}

// ---------- GCN epilogue ----------
// out[i,:] = xw[i,:] * rdeg[i] + bias   (self-loop term + bias), d=64
__global__ void gcn_init(const float* __restrict__ xw, const float* __restrict__ rdeg,
                         const float* __restrict__ bias, float* __restrict__ out, int n16) {
    int t = blockIdx.x * blockDim.x + threadIdx.x;
    if (t >= n16) return;
    int i = t >> 4;
    int c = (t & 15) << 2;
    float4 v = *(const float4*)(xw + (size_t)i * 64 + c);
    float4 b = *(const float4*)(bias + c);
    float r = rdeg[i];
    float4 o;
    o.x = v.x * r + b.x; o.y = v.y * r + b.y;
    o.z = v.z * r + b.z; o.w = v.w * r + b.w;
    *(float4*)(out + (size_t)i * 64 + c) = o;
}

// fused mu+ls edge scatter: out[dst] += dinv[src]*dinv[dst] * xw[src]
__global__ void gcn_scatter(const float* __restrict__ xwmu, const float* __restrict__ xwls,
                            const unsigned int* __restrict__ w, const int* __restrict__ sp,
                            const float* __restrict__ dinv,
                            float* __restrict__ omu, float* __restrict__ ols, int E) {
    long long t = (long long)blockIdx.x * blockDim.x + threadIdx.x;
    if (t >= (long long)E * 32) return;
    int e = (int)(t >> 5);
    int c = (int)(t & 31);
    int st = *sp;
    int s  = (int)w[(size_t)e * st];
    int dd = (int)w[(size_t)(E + e) * st];
    float nrm = dinv[s] * dinv[dd];
    const float* xw = (c < 16) ? xwmu : xwls;
    float* out      = (c < 16) ? omu  : ols;
    int cc = (c & 15) << 2;
    float4 v = *(const float4*)(xw + (size_t)s * 64 + cc);
    float* o = out + (size_t)dd * 64 + cc;
    atomicAdd(o + 0, nrm * v.x);
    atomicAdd(o + 1, nrm * v.y);
    atomicAdd(o + 2, nrm * v.z);
    atomicAdd(o + 3, nrm * v.w);
}

// ---------- launch ----------
extern "C" void kernel_launch(void* const* d_in, const int* in_sizes, int n_in,
                              void* d_out, int out_size, void* d_ws, size_t ws_size,
                              hipStream_t stream) {
    const float* x = (const float*)d_in[0];
    const unsigned int* ei_w = (const unsigned int*)d_in[1];
    // E robust to int32 element-count (3.2M) and int64 word-count (6.4M)
    const int E = (in_sizes[1] >= 6400000) ? in_sizes[1] / 4 : in_sizes[1] / 2;

    const size_t Nn = (size_t)in_sizes[0] / 128;   // 100000

    // f32 weights, used directly from d_in
    const float* w1l = (const float*)d_in[2];
    const float* w1r = (const float*)d_in[3];
    const float* b1f = (const float*)d_in[4];
    const float* w2l = (const float*)d_in[5];
    const float* w2r = (const float*)d_in[6];
    const float* b2f = (const float*)d_in[7];
    const float* wmu = (const float*)d_in[8];
    const float* bmuf = (const float*)d_in[9];
    const float* wls = (const float*)d_in[10];
    const float* blsf = (const float*)d_in[11];

    float* ws = (float*)d_ws;
    float* cnt  = ws;
    float* dinv = ws + Nn;
    float* rdeg = ws + 2 * Nn;
    float* rm   = ws + 3 * Nn;
    int*   esp  = (int*)(ws + 4 * Nn);          // 1 int slot, pad to 16 floats
    float* agg  = ws + 4 * Nn + 16;             // [Nn,256] (layer1 uses first 128 cols)
    float* h1   = agg + Nn * 256;               // [Nn,256]
    float* h2   = h1 + Nn * 256;                // [Nn,128]
    // aliases after layer-2 GEMM consumes agg:
    float* xwmu = agg;                          // [Nn,64]
    float* xwls = agg + Nn * 64;                // [Nn,64]
    // outputs written straight into d_out: mu then logstd
    float* omu = (float*)d_out;
    float* ols = omu + Nn * 64;
    // total ws: Nn*644 + 16 floats = 257.6 MB

    const int B = 256;

    hipMemsetAsync(cnt, 0, Nn * 4, stream);
    hipMemsetAsync(agg, 0, Nn * 128 * 4, stream);

    detect_estride<<<1, B, 0, stream>>>(ei_w, esp);

    count_edges<<<(E + B - 1) / B, B, 0, stream>>>(ei_w, esp, cnt, E);
    node_stats<<<((int)Nn + B - 1) / B, B, 0, stream>>>(cnt, dinv, rdeg, rm, (int)Nn);

    // ---- SAGE layer 1: d=128 -> 256
    long long t1 = (long long)E << 5;
    scatter_f32<<<(int)((t1 + B - 1) / B), B, 0, stream>>>(x, ei_w, esp, agg, E, 5);
    gemm_tile<true, true><<<dim3(4, 1563), B, 0, stream>>>(
        agg, x, w1l, w1r, b1f, rm, h1, (int)Nn, 256, 128);

    // ---- SAGE layer 2: d=256 -> 128
    hipMemsetAsync(agg, 0, Nn * 256 * 4, stream);
    long long t2 = (long long)E << 6;
    scatter_f32<<<(int)((t2 + B - 1) / B), B, 0, stream>>>(h1, ei_w, esp, agg, E, 6);
    gemm_tile<true, true><<<dim3(2, 1563), B, 0, stream>>>(
        agg, h1, w2l, w2r, b2f, rm, h2, (int)Nn, 128, 256);

    // ---- GCN heads: h2 @ W  (128 -> 64), bias applied in gcn_init
    gemm_tile<false, false><<<dim3(1, 1563), B, 0, stream>>>(
        h2, nullptr, wmu, nullptr, nullptr, nullptr, xwmu, (int)Nn, 64, 128);
    gemm_tile<false, false><<<dim3(1, 1563), B, 0, stream>>>(
        h2, nullptr, wls, nullptr, nullptr, nullptr, xwls, (int)Nn, 64, 128);

    int n16 = (int)(Nn * 16);
    gcn_init<<<(n16 + B - 1) / B, B, 0, stream>>>(xwmu, rdeg, bmuf, omu, n16);
    gcn_init<<<(n16 + B - 1) / B, B, 0, stream>>>(xwls, rdeg, blsf, ols, n16);

    long long t3 = (long long)E * 32;
    gcn_scatter<<<(int)((t3 + B - 1) / B), B, 0, stream>>>(
        xwmu, xwls, ei_w, esp, dinv, omu, ols, E);
}

// Round 15
// 1387.527 us; speedup vs baseline: 8.1906x; 8.1906x over previous
//
#include <hip/hip_runtime.h>
#include <cstdint>
#include <cstddef>

// f32 device tensors (proven R13). Edge buffer read in place with runtime
// stride detection (2=int64 low-word, 1=int32).

// ---------- edge dtype detection ----------
__global__ void detect_estride(const unsigned int* __restrict__ w, int* __restrict__ sp) {
    __shared__ int nz;
    if (threadIdx.x == 0) nz = 0;
    __syncthreads();
    int my = 0;
    for (int i = threadIdx.x; i < 4096; i += 256)
        if (w[2 * i + 1] != 0u) my++;
    if (my) atomicAdd(&nz, my);
    __syncthreads();
    if (threadIdx.x == 0) *sp = (nz == 0) ? 2 : 1;
}

// ---------- CSR build ----------
__global__ void deg_count(const unsigned int* __restrict__ w, const int* __restrict__ sp,
                          int* __restrict__ deg, int E) {
    int e = blockIdx.x * blockDim.x + threadIdx.x;
    if (e >= E) return;
    int st = *sp;
    atomicAdd(&deg[(int)w[(size_t)(E + e) * st]], 1);
}

__global__ void node_stats(const int* __restrict__ deg, float* __restrict__ dinv,
                           float* __restrict__ rdeg, float* __restrict__ rm, int n) {
    int i = blockIdx.x * blockDim.x + threadIdx.x;
    if (i >= n) return;
    float c = (float)deg[i];
    float d = c + 1.0f;
    dinv[i] = rsqrtf(d);
    rdeg[i] = 1.0f / d;
    rm[i]   = 1.0f / fmaxf(c, 1.0f);
}

// single-block exclusive scan: rowptr[0..n] from deg[0..n)
__global__ void scan_rowptr(const int* __restrict__ deg, int* __restrict__ rowptr, int n) {
    __shared__ int buf[1024];
    __shared__ int carry;
    int tid = threadIdx.x;
    if (tid == 0) carry = 0;
    __syncthreads();
    for (int base = 0; base < n; base += 1024) {
        int idx = base + tid;
        int v = (idx < n) ? deg[idx] : 0;
        buf[tid] = v;
        __syncthreads();
#pragma unroll
        for (int off = 1; off < 1024; off <<= 1) {
            int t = (tid >= off) ? buf[tid - off] : 0;
            __syncthreads();
            buf[tid] += t;
            __syncthreads();
        }
        if (idx < n) rowptr[idx] = carry + buf[tid] - v;   // exclusive
        int total = buf[1023];
        __syncthreads();
        if (tid == 0) carry += total;
        __syncthreads();
    }
    if (tid == 0) rowptr[n] = carry;
}

__global__ void csr_fill(const unsigned int* __restrict__ w, const int* __restrict__ sp,
                         const int* __restrict__ rowptr, int* __restrict__ cursor,
                         int* __restrict__ csr_src, int E) {
    int e = blockIdx.x * blockDim.x + threadIdx.x;
    if (e >= E) return;
    int st = *sp;
    int s  = (int)w[(size_t)e * st];
    int dd = (int)w[(size_t)(E + e) * st];
    int slot = atomicAdd(&cursor[dd], 1);
    csr_src[rowptr[dd] + slot] = s;
}

// ---------- CSR gather: out[n,:] = sum_{s in N(n)} feat[s,:]   (d=128) ----------
// one 128-thread block per node; coalesced 512B row reads, single coalesced write
__global__ void gather128(const float* __restrict__ feat, const int* __restrict__ rowptr,
                          const int* __restrict__ csr_src, float* __restrict__ out, int n) {
    int node = blockIdx.x;
    if (node >= n) return;
    int t = threadIdx.x;
    int b = rowptr[node], e = rowptr[node + 1];
    float acc = 0.f;
    for (int i = b; i < e; ++i) {
        int s = csr_src[i];
        acc += feat[(size_t)s * 128 + t];
    }
    out[(size_t)node * 128 + t] = acc;
}

// ---------- GCN heads gather (d=64, mu+ls fused) ----------
// out[n] = rdeg[n]*xw[n] + bias + dinv[n]*sum_{s} dinv[s]*xw[s]
__global__ void gcn_gather(const float* __restrict__ xwmu, const float* __restrict__ xwls,
                           const int* __restrict__ rowptr, const int* __restrict__ csr_src,
                           const float* __restrict__ dinv, const float* __restrict__ rdeg,
                           const float* __restrict__ bmu, const float* __restrict__ bls,
                           float* __restrict__ omu, float* __restrict__ ols, int n) {
    int node = blockIdx.x;
    if (node >= n) return;
    int t = threadIdx.x;                 // 128: t<64 -> mu, t>=64 -> ls
    const float* xw  = (t < 64) ? xwmu : xwls;
    const float* bia = (t < 64) ? bmu  : bls;
    float* outp      = (t < 64) ? omu  : ols;
    int c = t & 63;
    int b = rowptr[node], e = rowptr[node + 1];
    float acc = 0.f;
    for (int i = b; i < e; ++i) {
        int s = csr_src[i];
        acc += dinv[s] * xw[(size_t)s * 64 + c];
    }
    float self = xw[(size_t)node * 64 + c];
    outp[(size_t)node * 64 + c] = rdeg[node] * self + bia[c] + dinv[node] * acc;
}

// ---------- fused GEMM ----------
// C = act( scale(A1)@B1 [+ A2@B2] [+ rscale*A2 (EPIADD)] [+ bias] )
// BM=64, BN=64, BK=32, 256 threads, 4x4 micro-tile.
template<bool TWO, bool RELU, bool EPIADD>
__global__ __launch_bounds__(256)
void gemm_tile(const float* __restrict__ A1, const float* __restrict__ A2,
               const float* __restrict__ B1, const float* __restrict__ B2,
               const float* __restrict__ bias, const float* __restrict__ rscale,
               float* __restrict__ C, int M, int Nc, int K) {
    __shared__ float As1[32][64];
    __shared__ float Bs1[32][64];
    __shared__ float As2[TWO ? 32 : 1][64];
    __shared__ float Bs2[TWO ? 32 : 1][64];

    const int tid  = threadIdx.x;
    const int row0 = blockIdx.y * 64;
    const int col0 = blockIdx.x * 64;
    const int crow = (tid >> 4) << 2;
    const int ccol = (tid & 15) << 2;

    float acc[4][4] = {};

    for (int k0 = 0; k0 < K; k0 += 32) {
#pragma unroll
        for (int i = 0; i < 2; ++i) {
            int idx = tid + i * 256;
            int r  = idx >> 3;
            int kc = (idx & 7) << 2;
            int grow = row0 + r;
            if (grow > M - 1) grow = M - 1;
            float sc = (!EPIADD && rscale) ? rscale[grow] : 1.0f;
            float4 a = *(const float4*)(A1 + (size_t)grow * K + k0 + kc);
            As1[kc + 0][r] = a.x * sc;
            As1[kc + 1][r] = a.y * sc;
            As1[kc + 2][r] = a.z * sc;
            As1[kc + 3][r] = a.w * sc;
            if constexpr (TWO) {
                float4 a2 = *(const float4*)(A2 + (size_t)grow * K + k0 + kc);
                As2[kc + 0][r] = a2.x;
                As2[kc + 1][r] = a2.y;
                As2[kc + 2][r] = a2.z;
                As2[kc + 3][r] = a2.w;
            }
        }
#pragma unroll
        for (int i = 0; i < 2; ++i) {
            int idx = tid + i * 256;
            int kk = idx >> 4;
            int c4 = (idx & 15) << 2;
            *(float4*)&Bs1[kk][c4] = *(const float4*)(B1 + (size_t)(k0 + kk) * Nc + col0 + c4);
            if constexpr (TWO)
                *(float4*)&Bs2[kk][c4] = *(const float4*)(B2 + (size_t)(k0 + kk) * Nc + col0 + c4);
        }
        __syncthreads();

#pragma unroll
        for (int k = 0; k < 32; ++k) {
            float4 a1 = *(const float4*)&As1[k][crow];
            float4 b1 = *(const float4*)&Bs1[k][ccol];
            float av[4] = {a1.x, a1.y, a1.z, a1.w};
            float bv[4] = {b1.x, b1.y, b1.z, b1.w};
#pragma unroll
            for (int r = 0; r < 4; ++r)
#pragma unroll
                for (int c = 0; c < 4; ++c)
                    acc[r][c] += av[r] * bv[c];
            if constexpr (TWO) {
                float4 a2 = *(const float4*)&As2[k][crow];
                float4 b2 = *(const float4*)&Bs2[k][ccol];
                float av2[4] = {a2.x, a2.y, a2.z, a2.w};
                float bv2[4] = {b2.x, b2.y, b2.z, b2.w};
#pragma unroll
                for (int r = 0; r < 4; ++r)
#pragma unroll
                    for (int c = 0; c < 4; ++c)
                        acc[r][c] += av2[r] * bv2[c];
            }
        }
        __syncthreads();
    }

    float bv[4] = {0.f, 0.f, 0.f, 0.f};
    if (bias) {
        float4 b = *(const float4*)(bias + col0 + ccol);
        bv[0] = b.x; bv[1] = b.y; bv[2] = b.z; bv[3] = b.w;
    }
#pragma unroll
    for (int r = 0; r < 4; ++r) {
        int row = row0 + crow + r;
        if (row < M) {
            float4 o;
            o.x = acc[r][0] + bv[0];
            o.y = acc[r][1] + bv[1];
            o.z = acc[r][2] + bv[2];
            o.w = acc[r][3] + bv[3];
            if constexpr (EPIADD) {
                float rs = rscale[row];
                float4 g = *(const float4*)(A2 + (size_t)row * Nc + col0 + ccol);
                o.x += rs * g.x; o.y += rs * g.y;
                o.z += rs * g.z; o.w += rs * g.w;
            }
            if constexpr (RELU) {
                o.x = fmaxf(o.x, 0.f); o.y = fmaxf(o.y, 0.f);
                o.z = fmaxf(o.z, 0.f); o.w = fmaxf(o.w, 0.f);
            }
            *(float4*)(C + (size_t)row * Nc + col0 + ccol) = o;
        }
    }
}

// ---------- launch ----------
extern "C" void kernel_launch(void* const* d_in, const int* in_sizes, int n_in,
                              void* d_out, int out_size, void* d_ws, size_t ws_size,
                              hipStream_t stream) {
    const float* x = (const float*)d_in[0];
    const unsigned int* ei_w = (const unsigned int*)d_in[1];
    const int E = (in_sizes[1] >= 6400000) ? in_sizes[1] / 4 : in_sizes[1] / 2;
    const size_t Nn = (size_t)in_sizes[0] / 128;   // 100000

    const float* w1l = (const float*)d_in[2];
    const float* w1r = (const float*)d_in[3];
    const float* b1f = (const float*)d_in[4];
    const float* w2l = (const float*)d_in[5];
    const float* w2r = (const float*)d_in[6];
    const float* b2f = (const float*)d_in[7];
    const float* wmu = (const float*)d_in[8];
    const float* bmuf = (const float*)d_in[9];
    const float* wls = (const float*)d_in[10];
    const float* blsf = (const float*)d_in[11];

    float* wsf = (float*)d_ws;
    int*   wsi = (int*)d_ws;

    int*   deg    = wsi;                         // [Nn]
    float* dinv   = wsf + Nn;
    float* rdeg   = wsf + 2 * Nn;
    float* rm     = wsf + 3 * Nn;
    int*   rowptr = wsi + 4 * Nn;                // [Nn+1] (pad 16)
    int*   cursor = wsi + 5 * Nn + 16;           // [Nn]
    int*   esp    = wsi + 6 * Nn + 16;           // [1] (pad 16)
    int*   csrs   = wsi + 6 * Nn + 32;           // [E]
    float* agg    = wsf + 6 * Nn + 32 + E;       // [Nn,128]; reused as g2
    float* h1     = agg + Nn * 128;              // [Nn,256]
    float* t2     = h1 + Nn * 256;               // [Nn,128]; reused as h2
    float* h2     = t2;
    float* g2     = agg;
    float* xwmu   = h1;                          // [Nn,64]  (h1 dead after h2)
    float* xwls   = h1 + Nn * 64;                // [Nn,64]
    float* omu    = (float*)d_out;
    float* ols    = omu + Nn * 64;
    // total ws: (518*Nn + E + 32)*4B = 213.7 MB

    const int B = 256;

    hipMemsetAsync(deg, 0, Nn * 4, stream);
    hipMemsetAsync(cursor, 0, Nn * 4, stream);

    detect_estride<<<1, B, 0, stream>>>(ei_w, esp);
    deg_count<<<(E + B - 1) / B, B, 0, stream>>>(ei_w, esp, deg, E);
    node_stats<<<((int)Nn + B - 1) / B, B, 0, stream>>>(deg, dinv, rdeg, rm, (int)Nn);
    scan_rowptr<<<1, 1024, 0, stream>>>(deg, rowptr, (int)Nn);
    csr_fill<<<(E + B - 1) / B, B, 0, stream>>>(ei_w, esp, rowptr, cursor, csrs, E);

    // ---- SAGE layer 1: aggregate(x) then fused GEMM (d 128 -> 256)
    gather128<<<(int)Nn, 128, 0, stream>>>(x, rowptr, csrs, agg, (int)Nn);
    gemm_tile<true, true, false><<<dim3(4, 1563), B, 0, stream>>>(
        agg, x, w1l, w1r, b1f, rm, h1, (int)Nn, 256, 128);

    // ---- SAGE layer 2 (transform-first): t2 = h1@W2l, aggregate, fuse
    gemm_tile<false, false, false><<<dim3(2, 1563), B, 0, stream>>>(
        h1, nullptr, w2l, nullptr, nullptr, nullptr, t2, (int)Nn, 128, 256);
    gather128<<<(int)Nn, 128, 0, stream>>>(t2, rowptr, csrs, g2, (int)Nn);
    gemm_tile<false, true, true><<<dim3(2, 1563), B, 0, stream>>>(
        h1, g2, w2r, nullptr, b2f, rm, h2, (int)Nn, 128, 256);

    // ---- GCN heads: xw = h2@W, then normalized gather epilogue
    gemm_tile<false, false, false><<<dim3(1, 1563), B, 0, stream>>>(
        h2, nullptr, wmu, nullptr, nullptr, nullptr, xwmu, (int)Nn, 64, 128);
    gemm_tile<false, false, false><<<dim3(1, 1563), B, 0, stream>>>(
        h2, nullptr, wls, nullptr, nullptr, nullptr, xwls, (int)Nn, 64, 128);

    gcn_gather<<<(int)Nn, 128, 0, stream>>>(
        xwmu, xwls, rowptr, csrs, dinv, rdeg, bmuf, blsf, omu, ols, (int)Nn);
}